// Round 5
// baseline (120.111 us; speedup 1.0000x reference)
//
#include <hip/hip_runtime.h>

#define DIM 128
#define NROWS 2048
#define NDP 64
#define WSTRIDE 72  // wbuf row stride in f16 (64 + 8 pad: keeps 16B alignment, spreads banks)

typedef _Float16 h2 __attribute__((ext_vector_type(2)));
typedef _Float16 f16x8 __attribute__((ext_vector_type(8)));
typedef float f32x4 __attribute__((ext_vector_type(4)));

static __device__ __forceinline__ h2 u2h(unsigned u) { return __builtin_bit_cast(h2, u); }
static __device__ __forceinline__ unsigned h2u(h2 h) { return __builtin_bit_cast(unsigned, h); }

// ---------------------------------------------------------------------------
// One kernel, grid (32,32) x 256 thr, 64i x 64j output tile, 3 blocks/CU.
// Phase A: per-block MFMA GEMM builds f16 d-pair tables in LDS:
//   his2[dp][i] = pack(hi[2dp][i], hi[2dp+1][i]),  hjs2 likewise + b1.
//   Computed as hiT = W1_side^T @ z^T so the MFMA C-layout (col=lane&15 -> i,
//   row=quad*4+reg -> d) gives each lane 4 consecutive d = 2 d-pairs.
//   W1 chunk staged transposed-f16 in wbuf ([d][k], ds_read_b128 A-frags);
//   z B-frags loaded straight from global (L2-resident) and cvt to f16.
// Phase B: out[i][j] = b2 + sum_dp dot2(relu(his2[dp][i]+hjs2[dp][j]), w2[dp])
//   via v_pk_add_f16 + v_pk_max_f16 + v_dot2_f32_f16 (1.5 instr / element).
// ---------------------------------------------------------------------------
__global__ __launch_bounds__(256, 3) void fused_kernel(
    const float* __restrict__ z_i, const float* __restrict__ z_j,
    const float* __restrict__ W1, const float* __restrict__ b1,
    const float* __restrict__ W2, const float* __restrict__ b2p,
    float* __restrict__ out) {
  __shared__ _Float16 wbuf[DIM * WSTRIDE];  // 18 KB  W1-side k-chunk, [d][k]
  __shared__ unsigned his2[NDP * 64];       // 16 KB  [dp][i]
  __shared__ unsigned hjs2[NDP * 64];       // 16 KB  [dp][j]
  __shared__ unsigned w2s[NDP];             // 256 B

  const int t = threadIdx.x;
  const int ibase = blockIdx.y * 64;
  const int jbase = blockIdx.x * 64;

  if (t < NDP)
    w2s[t] = h2u((h2){(_Float16)W2[2 * t], (_Float16)W2[2 * t + 1]});

  const int w = t >> 6;           // wave 0..3 -> d-tiles {2w, 2w+1}
  const int quad = (t >> 4) & 3;  // MFMA quad
  const int n = t & 15;           // MFMA lane-in-quad (i / col)
  const int sd = t & 127;         // staging: d owned by this thread
  const int sgb = (t >> 7) * 4;   // staging: k-group base

#pragma unroll
  for (int side = 0; side < 2; ++side) {
    const float* z = side ? z_j : z_i;
    const int rbase = side ? jbase : ibase;
    f32x4 acc[2][4];
#pragma unroll
    for (int a = 0; a < 2; ++a)
#pragma unroll
      for (int b = 0; b < 4; ++b) acc[a][b] = (f32x4){0.f, 0.f, 0.f, 0.f};

#pragma unroll
    for (int chunk = 0; chunk < 2; ++chunk) {
      const int c0 = chunk * 64;
      __syncthreads();  // wbuf reuse guard
      // stage wbuf[d][k-c0] = (f16) W1[side*128 + c0 + k][d]; 4 tasks/thread,
      // each = 8 lane-coalesced dword loads + 1 ds_write_b128.
#pragma unroll
      for (int g = 0; g < 4; ++g) {
        const int gg = sgb + g;
        const float* wp = W1 + (size_t)(side * DIM + c0 + gg * 8) * DIM + sd;
        _Float16 v[8];
#pragma unroll
        for (int jx = 0; jx < 8; ++jx) v[jx] = (_Float16)wp[jx * DIM];
        *(f16x8*)(wbuf + sd * WSTRIDE + gg * 8) =
            (f16x8){v[0], v[1], v[2], v[3], v[4], v[5], v[6], v[7]};
      }
      __syncthreads();

#pragma unroll
      for (int s = 0; s < 2; ++s) {
        const int kabs = c0 + s * 32;
        f16x8 af[2];  // A = W1^T fragments: A[m=d=lane&15 of tile][k=quad*8+j]
#pragma unroll
        for (int dtl = 0; dtl < 2; ++dtl) {
          const int d = (2 * w + dtl) * 16 + n;
          af[dtl] = *(const f16x8*)(wbuf + d * WSTRIDE + (s * 32 + quad * 8));
        }
#pragma unroll
        for (int it = 0; it < 4; ++it) {
          // B = z^T fragment: B[k=quad*8+j][n=i=lane&15]
          const float* zp =
              z + (size_t)(rbase + it * 16 + n) * DIM + kabs + quad * 8;
          const float4 a = *(const float4*)zp;
          const float4 b = *(const float4*)(zp + 4);
          const f16x8 bf = {(_Float16)a.x, (_Float16)a.y, (_Float16)a.z,
                            (_Float16)a.w, (_Float16)b.x, (_Float16)b.y,
                            (_Float16)b.z, (_Float16)b.w};
#pragma unroll
          for (int dtl = 0; dtl < 2; ++dtl)
            acc[dtl][it] = __builtin_amdgcn_mfma_f32_16x16x32_f16(
                af[dtl], bf, acc[dtl][it], 0, 0, 0);
        }
      }
    }

    // writeout: lane holds D[d][i] with d = dt*16 + quad*4 + reg, i = it*16+n
    unsigned* dest = side ? hjs2 : his2;
#pragma unroll
    for (int dtl = 0; dtl < 2; ++dtl) {
      const int dt = 2 * w + dtl;
      float4 bb = {0.f, 0.f, 0.f, 0.f};
      if (side) bb = *(const float4*)(b1 + dt * 16 + quad * 4);
      const int dp0 = dt * 8 + quad * 2;
#pragma unroll
      for (int it = 0; it < 4; ++it) {
        const f32x4 c = acc[dtl][it];
        const int i = it * 16 + n;
        dest[dp0 * 64 + i] =
            h2u((h2){(_Float16)(c.x + bb.x), (_Float16)(c.y + bb.y)});
        dest[(dp0 + 1) * 64 + i] =
            h2u((h2){(_Float16)(c.z + bb.z), (_Float16)(c.w + bb.w)});
      }
    }
  }
  __syncthreads();

  // ---- phase B ----
  const int tx = t & 15;
  const int ty = t >> 4;
  float facc[4][4];
#pragma unroll
  for (int ii = 0; ii < 4; ++ii)
#pragma unroll
    for (int jj = 0; jj < 4; ++jj) facc[ii][jj] = 0.f;

  const h2 zero = {(_Float16)0.f, (_Float16)0.f};
#pragma unroll 2
  for (int dpg = 0; dpg < 16; ++dpg) {
    const uint4 w4 = *(const uint4*)(w2s + dpg * 4);  // broadcast
    const h2 wp[4] = {u2h(w4.x), u2h(w4.y), u2h(w4.z), u2h(w4.w)};
#pragma unroll
    for (int q = 0; q < 4; ++q) {
      const int dp = dpg * 4 + q;
      const uint4 hu = *(const uint4*)(his2 + dp * 64 + ty * 4);  // broadcast
      const uint4 ju = *(const uint4*)(hjs2 + dp * 64 + tx * 4);  // 2-way free
      const h2 hiv[4] = {u2h(hu.x), u2h(hu.y), u2h(hu.z), u2h(hu.w)};
      const h2 hjv[4] = {u2h(ju.x), u2h(ju.y), u2h(ju.z), u2h(ju.w)};
#pragma unroll
      for (int ii = 0; ii < 4; ++ii) {
#pragma unroll
        for (int jj = 0; jj < 4; ++jj) {
          h2 s2 = hiv[ii] + hjv[jj];                 // v_pk_add_f16
          s2 = __builtin_elementwise_max(s2, zero);  // v_pk_max_f16
          facc[ii][jj] = __builtin_amdgcn_fdot2(s2, wp[q], facc[ii][jj], false);
        }
      }
    }
  }

  const float bias = *b2p;
#pragma unroll
  for (int ii = 0; ii < 4; ++ii) {
    float* o = out + (size_t)(ibase + ty * 4 + ii) * NROWS + jbase + tx * 4;
    *(float4*)o = (float4){facc[ii][0] + bias, facc[ii][1] + bias,
                           facc[ii][2] + bias, facc[ii][3] + bias};
  }
}

extern "C" void kernel_launch(void* const* d_in, const int* in_sizes, int n_in,
                              void* d_out, int out_size, void* d_ws, size_t ws_size,
                              hipStream_t stream) {
  const float* z_i = (const float*)d_in[0];
  const float* z_j = (const float*)d_in[1];
  const float* W1  = (const float*)d_in[2];
  const float* b1  = (const float*)d_in[3];
  const float* W2  = (const float*)d_in[4];
  const float* b2  = (const float*)d_in[5];
  float* out = (float*)d_out;

  fused_kernel<<<dim3(32, 32), 256, 0, stream>>>(z_i, z_j, W1, b1, W2, b2, out);
}

// Round 6
// 106.307 us; speedup vs baseline: 1.1298x; 1.1298x over previous
//
#include <hip/hip_runtime.h>

#define DIM 128
#define NROWS 2048
#define NDP 64  // d-pairs

typedef float v2f __attribute__((ext_vector_type(2)));
typedef _Float16 h2 __attribute__((ext_vector_type(2)));

static __device__ __forceinline__ h2 u2h(unsigned u) { return __builtin_bit_cast(h2, u); }
static __device__ __forceinline__ unsigned h2u(h2 h) { return __builtin_bit_cast(unsigned, h); }

// ---------------------------------------------------------------------------
// prep (identical to R4): hi2T[dp][n] = half2(hi[2dp][n], hi[2dp+1][n]),
// hj2T likewise + b1 folded. grid (256 row-tiles of 8, 2 sides) x 256 thr.
// ---------------------------------------------------------------------------
__global__ __launch_bounds__(256) void prep_kernel(
    const float* __restrict__ z_i, const float* __restrict__ z_j,
    const float* __restrict__ W1, const float* __restrict__ b1,
    unsigned* __restrict__ hi2T, unsigned* __restrict__ hj2T) {
  __shared__ float zs[8 * DIM];  // 4 KB

  const int t = threadIdx.x;
  const int side = blockIdx.y;
  const int rowbase = blockIdx.x * 8;

  const float* z = (side ? z_j : z_i) + (size_t)rowbase * DIM;
  ((float4*)zs)[t] = ((const float4*)z)[t];
  __syncthreads();

  const int dp = t & 63;
  const int rg = t >> 6;
  const float* wcol = W1 + side * (DIM * DIM) + dp * 2;
  const float* z0 = zs + (rg * 2) * DIM;
  const float* z1 = z0 + DIM;

  v2f acc0 = {0.f, 0.f}, acc1 = {0.f, 0.f};
#pragma unroll 8
  for (int k = 0; k < DIM; ++k) {
    const v2f wv = *(const v2f*)(wcol + (size_t)k * DIM);
    const float a = z0[k], b = z1[k];
    acc0 = __builtin_elementwise_fma(wv, (v2f){a, a}, acc0);
    acc1 = __builtin_elementwise_fma(wv, (v2f){b, b}, acc1);
  }

  if (side) {
    const v2f bb = *(const v2f*)(b1 + dp * 2);
    acc0 += bb;
    acc1 += bb;
  }
  unsigned* dst = (side ? hj2T : hi2T) + (size_t)dp * NROWS + rowbase + rg * 2;
  dst[0] = h2u((h2){(_Float16)acc0.x, (_Float16)acc0.y});
  dst[1] = h2u((h2){(_Float16)acc1.x, (_Float16)acc1.y});
}

// ---------------------------------------------------------------------------
// score v6: out[i][j] = b2 + sum_dp dot2(relu(hi2[dp][i]+hj2[dp][j]), w2[dp])
// Tile 64i x 128j, grid (16 jt, 32 it) = 512 blocks, 48.25 KB LDS -> 3/CU
// (12 waves/CU). Micro-tile 4i x 8j (two 4j halves at +0 and +64 so both
// LDS reads keep 16B lane-stride = 2-way = free). Per dp per thread:
// 3 ds_read_b128 + 96 VALU -> LDS pipe 75% of VALU -> VALU-bound.
// Core: v_pk_add_f16 + v_pk_max_f16 + v_dot2_f32_f16.
// ---------------------------------------------------------------------------
__global__ __launch_bounds__(256, 3) void score_kernel(
    const unsigned* __restrict__ hi2T, const unsigned* __restrict__ hj2T,
    const float* __restrict__ W2, const float* __restrict__ b2p,
    float* __restrict__ out) {
  __shared__ unsigned his2[NDP * 64];   // 16 KB  [dp][i]
  __shared__ unsigned hjs2[NDP * 128];  // 32 KB  [dp][j]
  __shared__ unsigned w2s[NDP];         // 256 B

  const int t = threadIdx.x;
  const int ibase = blockIdx.y * 64;
  const int jbase = blockIdx.x * 128;
  const float bias = *b2p;

  // stage hi tile: 4096 uints
#pragma unroll
  for (int rep = 0; rep < 4; ++rep) {
    const int idx = rep * 256 + t;
    const int dp = idx >> 4, c = (idx & 15) * 4;
    *(uint4*)(his2 + dp * 64 + c) =
        *(const uint4*)(hi2T + (size_t)dp * NROWS + ibase + c);
  }
  // stage hj tile: 8192 uints
#pragma unroll
  for (int rep = 0; rep < 8; ++rep) {
    const int idx = rep * 256 + t;
    const int dp = idx >> 5, c = (idx & 31) * 4;
    *(uint4*)(hjs2 + dp * 128 + c) =
        *(const uint4*)(hj2T + (size_t)dp * NROWS + jbase + c);
  }
  if (t < NDP) {
    const v2f wp = *(const v2f*)(W2 + t * 2);
    w2s[t] = h2u((h2){(_Float16)wp.x, (_Float16)wp.y});
  }
  __syncthreads();  // the only barrier

  const int tx = t & 15;   // j-group: 4 j's at jbase+tx*4 and jbase+64+tx*4
  const int ty = t >> 4;   // i-group: 4 i's

  float facc[4][8];
#pragma unroll
  for (int ii = 0; ii < 4; ++ii)
#pragma unroll
    for (int jj = 0; jj < 8; ++jj) facc[ii][jj] = 0.f;

  const h2 zero = {(_Float16)0.f, (_Float16)0.f};
#pragma unroll 2
  for (int dpg = 0; dpg < 16; ++dpg) {
    const uint4 w4 = *(const uint4*)(w2s + dpg * 4);  // broadcast
    const h2 wp[4] = {u2h(w4.x), u2h(w4.y), u2h(w4.z), u2h(w4.w)};
#pragma unroll
    for (int q = 0; q < 4; ++q) {
      const int dp = dpg * 4 + q;
      const uint4 hu = *(const uint4*)(his2 + dp * 64 + ty * 4);        // bcast
      const uint4 j0 = *(const uint4*)(hjs2 + dp * 128 + tx * 4);       // free
      const uint4 j1 = *(const uint4*)(hjs2 + dp * 128 + 64 + tx * 4);  // free
      const h2 hiv[4] = {u2h(hu.x), u2h(hu.y), u2h(hu.z), u2h(hu.w)};
      const h2 hjv[8] = {u2h(j0.x), u2h(j0.y), u2h(j0.z), u2h(j0.w),
                         u2h(j1.x), u2h(j1.y), u2h(j1.z), u2h(j1.w)};
#pragma unroll
      for (int ii = 0; ii < 4; ++ii) {
#pragma unroll
        for (int jj = 0; jj < 8; ++jj) {
          h2 s2 = hiv[ii] + hjv[jj];                 // v_pk_add_f16
          s2 = __builtin_elementwise_max(s2, zero);  // v_pk_max_f16
          facc[ii][jj] = __builtin_amdgcn_fdot2(s2, wp[q], facc[ii][jj], false);
        }
      }
    }
  }

#pragma unroll
  for (int ii = 0; ii < 4; ++ii) {
    float* o = out + (size_t)(ibase + ty * 4 + ii) * NROWS + jbase + tx * 4;
    *(float4*)o = (float4){facc[ii][0] + bias, facc[ii][1] + bias,
                           facc[ii][2] + bias, facc[ii][3] + bias};
    *(float4*)(o + 64) = (float4){facc[ii][4] + bias, facc[ii][5] + bias,
                                  facc[ii][6] + bias, facc[ii][7] + bias};
  }
}

extern "C" void kernel_launch(void* const* d_in, const int* in_sizes, int n_in,
                              void* d_out, int out_size, void* d_ws, size_t ws_size,
                              hipStream_t stream) {
  const float* z_i = (const float*)d_in[0];
  const float* z_j = (const float*)d_in[1];
  const float* W1  = (const float*)d_in[2];
  const float* b1  = (const float*)d_in[3];
  const float* W2  = (const float*)d_in[4];
  const float* b2  = (const float*)d_in[5];
  float* out = (float*)d_out;

  unsigned* hi2T = (unsigned*)d_ws;             // [64][2048] half2 -> 512 KB
  unsigned* hj2T = hi2T + (size_t)NDP * NROWS;  // [64][2048] half2 -> 512 KB

  prep_kernel<<<dim3(256, 2), 256, 0, stream>>>(z_i, z_j, W1, b1, hi2T, hj2T);
  score_kernel<<<dim3(16, 32), 256, 0, stream>>>(hi2T, hj2T, W2, b2, out);
}